// Round 5
// baseline (418.197 us; speedup 1.0000x reference)
//
#include <hip/hip_runtime.h>
#include <hip/hip_cooperative_groups.h>

namespace cg = cooperative_groups;

// LinearAttention (Performer/FAVOR+): B=8, T=S=8192, F=D=64, M=128 (2M=256 features)
// R5: single cooperative kernel (kv -> grid.sync -> finalize -> grid.sync -> qkv)
// to kill inter-dispatch ramp/drain. Fallback to the R4 3-kernel path if the
// cooperative launch is rejected.
//
// MFMA 16x16x32 bf16 layouts (measured, learn_hip m89/m91):
//   A-frag: lane holds A[m = lane&15][k = (lane>>4)*8 + j], j=0..7
//   B-frag: lane holds B[k = (lane>>4)*8 + j][n = lane&15]
//   C/D   : lane holds D[row = (lane>>4)*4 + reg][col = lane&15], reg=0..3

constexpr int NB = 8;
constexpr int NT = 8192;
constexpr float EPSF = 1e-9f;
constexpr float SCALE = 0.0625f;  // 1/sqrt(2*128)

typedef short s8v __attribute__((ext_vector_type(8)));
typedef short s4v __attribute__((ext_vector_type(4)));
typedef float f4v __attribute__((ext_vector_type(4)));

__device__ inline f4v mfma16(s8v a, s8v b, f4v c) {
  return __builtin_amdgcn_mfma_f32_16x16x32_bf16(a, b, c, 0, 0, 0);
}

__device__ inline short bf16_rne(float f) {
  unsigned u = __builtin_bit_cast(unsigned, f);
  u += 0x7fffu + ((u >> 16) & 1u);
  return (short)(u >> 16);
}
__device__ inline float bf16_to_f(short h) {
  unsigned u = ((unsigned)(unsigned short)h) << 16;
  return __builtin_bit_cast(float, u);
}

// ---- setup: split omega into bf16 hi/lo (Markidis 3-term split keeps the
// pre-exp x.omega GEMM at ~fp32 accuracy) ----
__global__ void setup_omega(const float* __restrict__ omega,
                            short* __restrict__ oh, short* __restrict__ ol) {
  int i = blockIdx.x * 256 + threadIdx.x;
  if (i >= 128 * 64) return;
  float w = omega[i];
  short h = bf16_rne(w);
  oh[i] = h;
  ol[i] = bf16_rne(w - bf16_to_f(h));
}

// ---- shared phi helpers ----
struct PhiRows {
  s8v ah0, al0, ah1, al1;  // x fragments (hi/lo) for ksteps 0,1
  float ssr[4];            // |x_row|^2/2 for rows quad*4+reg (C-row indexed)
  float ss;                // |x_row|^2/2 for this lane's own row (lane&15)
};

__device__ inline void split8(f4v a, f4v b, s8v& h, s8v& l) {
  float v[8] = {a.x, a.y, a.z, a.w, b.x, b.y, b.z, b.w};
#pragma unroll
  for (int j = 0; j < 8; ++j) {
    short hh = bf16_rne(v[j]);
    h[j] = hh;
    l[j] = bf16_rne(v[j] - bf16_to_f(hh));
  }
}

__device__ inline void load_phi_rows(const float* __restrict__ xrow_base, int lane, PhiRows& P) {
  const int r = lane & 15, q = lane >> 4;
  const float* p = xrow_base + r * 64 + q * 8;
  f4v u0 = *(const f4v*)(p);
  f4v u1 = *(const f4v*)(p + 4);
  f4v u2 = *(const f4v*)(p + 32);
  f4v u3 = *(const f4v*)(p + 36);
  float ss = u0.x * u0.x + u0.y * u0.y + u0.z * u0.z + u0.w * u0.w
           + u1.x * u1.x + u1.y * u1.y + u1.z * u1.z + u1.w * u1.w
           + u2.x * u2.x + u2.y * u2.y + u2.z * u2.z + u2.w * u2.w
           + u3.x * u3.x + u3.y * u3.y + u3.z * u3.z + u3.w * u3.w;
  ss += __shfl_xor(ss, 16, 64);
  ss += __shfl_xor(ss, 32, 64);
  ss *= 0.5f;
  P.ss = ss;
#pragma unroll
  for (int reg = 0; reg < 4; ++reg) P.ssr[reg] = __shfl(ss, q * 4 + reg, 64);
  split8(u0, u1, P.ah0, P.al0);
  split8(u2, u3, P.ah1, P.al1);
}

// xw C-tile, A = x rows (C: row = x-row q*4+reg, col = omega-row lane&15)
__device__ inline f4v phi_xw_tile(const PhiRows& P, const short* __restrict__ oh,
                                  const short* __restrict__ ol, int f0, int lane) {
  const int fr = f0 + (lane & 15);
  const int q = lane >> 4;
  s8v bh0 = *(const s8v*)(oh + fr * 64 + q * 8);
  s8v bh1 = *(const s8v*)(oh + fr * 64 + 32 + q * 8);
  s8v bl0 = *(const s8v*)(ol + fr * 64 + q * 8);
  s8v bl1 = *(const s8v*)(ol + fr * 64 + 32 + q * 8);
  f4v c = {0.f, 0.f, 0.f, 0.f};
  c = mfma16(P.ah0, bh0, c);
  c = mfma16(P.ah1, bh1, c);
  c = mfma16(P.al0, bh0, c);
  c = mfma16(P.al1, bh1, c);
  c = mfma16(P.ah0, bl0, c);
  c = mfma16(P.ah1, bl1, c);
  return c;
}

// xw C-tile, swapped: A = omega rows (C: row = omega-row q*4+reg, col = x-row lane&15).
__device__ inline f4v phi_xw_tile_T(const PhiRows& P, const short* __restrict__ oh,
                                    const short* __restrict__ ol, int f0, int lane) {
  const int fr = f0 + (lane & 15);
  const int q = lane >> 4;
  s8v ah0 = *(const s8v*)(oh + fr * 64 + q * 8);
  s8v ah1 = *(const s8v*)(oh + fr * 64 + 32 + q * 8);
  s8v al0 = *(const s8v*)(ol + fr * 64 + q * 8);
  s8v al1 = *(const s8v*)(ol + fr * 64 + 32 + q * 8);
  f4v c = {0.f, 0.f, 0.f, 0.f};
  c = mfma16(ah0, P.ah0, c);
  c = mfma16(ah1, P.ah1, c);
  c = mfma16(al0, P.ah0, c);
  c = mfma16(al1, P.ah1, c);
  c = mfma16(ah0, P.al0, c);
  c = mfma16(ah1, P.al1, c);
  return c;
}

constexpr int KF_P = 72;   // kft/v1t pitch in shorts
constexpr int QF_P = 264;  // qf pitch (shorts): 256 + 8 pad

// ================= fused cooperative kernel =================
__global__ __launch_bounds__(256, 4) void fused_all(
    const float* __restrict__ query, const float* __restrict__ value,
    const float* __restrict__ key, const short* __restrict__ oh,
    const short* __restrict__ ol, short* __restrict__ partial,
    short* __restrict__ kvfrag, float* __restrict__ out, int nblk) {
  __shared__ __align__(16) short smem[64 * QF_P];  // 33792 B, overlaid per phase
  const int tid = threadIdx.x, lane = tid & 63, w = tid >> 6;
  const int q = lane >> 4, r15 = lane & 15;
  cg::grid_group grid = cg::this_grid();

  // ---------- Phase A: kv partials (items: 8b x 64 s-chunks(128) x 2 halves) ----------
  {
    short* kft = smem;                 // [128][KF_P]
    short* v1t = smem + 128 * KF_P;    // [80][KF_P]
    // zero v1t pad rows 65..79 once (never overwritten below)
    for (int i = tid; i < 15 * KF_P; i += 256) v1t[65 * KF_P + i] = 0;
    for (int it = blockIdx.x; it < 1024; it += nblk) {
      const int b = it >> 7;
      const int cb = it & 127;
      const int fh = cb & 1;
      const int s0 = (cb >> 1) * 128;

      f4v acc[2][5];
#pragma unroll
      for (int j = 0; j < 2; ++j)
#pragma unroll
        for (int n = 0; n < 5; ++n) acc[j][n] = f4v{0.f, 0.f, 0.f, 0.f};

      for (int sc = 0; sc < 2; ++sc) {
        const int sbase = s0 + sc * 64;
        __syncthreads();  // protect previous GEMM / previous item's reads
        // stage v1t[d][s] (transposed, bf16)
        {
          const float* vb = value + ((size_t)b * NT + sbase) * 64;
#pragma unroll
          for (int i = 0; i < 4; ++i) {
            int e4 = tid + i * 256;
            f4v v4 = ((const f4v*)vb)[e4];
            int s = e4 >> 4, d0 = (e4 & 15) * 4;
            v1t[(d0 + 0) * KF_P + s] = bf16_rne(v4.x);
            v1t[(d0 + 1) * KF_P + s] = bf16_rne(v4.y);
            v1t[(d0 + 2) * KF_P + s] = bf16_rne(v4.z);
            v1t[(d0 + 3) * KF_P + s] = bf16_rne(v4.w);
          }
          if (tid < 64) v1t[64 * KF_P + tid] = (short)0x3F80;  // bf16(1.0)
        }
        // phi(k): wave w -> s-rows sbase+w*16..+15, 4 feature-tiles of its half
        {
          PhiRows P;
          load_phi_rows(key + ((size_t)b * NT + sbase + w * 16) * 64, lane, P);
#pragma unroll
          for (int ft = 0; ft < 4; ++ft) {
            f4v c = phi_xw_tile(P, oh, ol, fh * 64 + ft * 16, lane);
            s4v pk, nk;
#pragma unroll
            for (int reg = 0; reg < 4; ++reg) {
              float xw = c[reg];
              pk[reg] = bf16_rne((__expf(xw - P.ssr[reg]) + EPSF) * SCALE);
              nk[reg] = bf16_rne((__expf(-xw - P.ssr[reg]) + EPSF) * SCALE);
            }
            const int scol = w * 16 + q * 4;
            *(s4v*)(kft + (ft * 16 + r15) * KF_P + scol) = pk;
            *(s4v*)(kft + (64 + ft * 16 + r15) * KF_P + scol) = nk;
          }
        }
        __syncthreads();
        // GEMM: wave w accumulates local feats lf = w*32..+31 over 64 s
#pragma unroll
        for (int ks = 0; ks < 2; ++ks) {
          s8v bf[5];
#pragma unroll
          for (int n = 0; n < 5; ++n)
            bf[n] = *(const s8v*)(v1t + (n * 16 + r15) * KF_P + ks * 32 + q * 8);
#pragma unroll
          for (int j = 0; j < 2; ++j) {
            s8v a = *(const s8v*)(kft + (w * 32 + j * 16 + r15) * KF_P + ks * 32 + q * 8);
#pragma unroll
            for (int n = 0; n < 5; ++n) acc[j][n] = mfma16(a, bf[n], acc[j][n]);
          }
        }
      }
      // epilogue: bf16 partial, C row = lf (w*32+j*16+q*4+reg), col = d (n*16+r15)
      short* pb = partial + (size_t)it * (80 * 128);
#pragma unroll
      for (int j = 0; j < 2; ++j)
#pragma unroll
        for (int n = 0; n < 5; ++n) {
          int d = n * 16 + r15;
          int lf = w * 32 + j * 16 + q * 4;
          s4v pk;
#pragma unroll
          for (int reg = 0; reg < 4; ++reg) pk[reg] = bf16_rne(acc[j][n][reg]);
          *(s4v*)(pb + d * 128 + lf) = pk;
        }
    }
  }
  __threadfence();
  grid.sync();

  // ---------- Phase B: reduce partials -> kvfrag (B-fragment order) ----------
  for (int i = blockIdx.x * 256 + tid; i < 163840; i += nblk * 256) {
    int b = i / 20480;
    int rem = i - b * 20480;
    int d = rem >> 8;
    int m = rem & 255;
    int o = m & 127, sg = m >> 7;
    int fh = o >> 6;
    int lf = (o & 63) + (sg << 6);
    const short* p = partial + ((size_t)(b * 128 + fh)) * (80 * 128) + d * 128 + lf;
    float s = 0.f;
#pragma unroll 8
    for (int c = 0; c < 64; ++c) s += bf16_to_f(p[(size_t)c * 2 * (80 * 128)]);
    int ks = m >> 5, qq = (m >> 3) & 3, j = m & 7;
    int n = d >> 4, r = d & 15;
    int ln = qq * 16 + r;
    kvfrag[(((size_t)b * 40 + ks * 5 + n) * 64 + ln) * 8 + j] = bf16_rne(s);
  }
  __threadfence();
  grid.sync();

  // ---------- Phase C: qkv + normalize (items: 8b x 128 t-chunks(64)) ----------
  {
    short* qf = smem;  // [64][QF_P], wave-private rows -> no barriers
    for (int it = blockIdx.x; it < 1024; it += nblk) {
      const int b = it >> 7;
      const int t0 = (it & 127) * 64;
      __syncthreads();  // LDS reuse across phases/items (cheap)
      {
        PhiRows P;
        load_phi_rows(query + ((size_t)b * NT + t0 + w * 16) * 64, lane, P);
        const int t_loc = w * 16 + r15;
#pragma unroll
        for (int ft = 0; ft < 8; ++ft) {
          f4v c = phi_xw_tile_T(P, oh, ol, ft * 16, lane);
          s4v pk, nk;
#pragma unroll
          for (int reg = 0; reg < 4; ++reg) {
            float xw = c[reg];
            pk[reg] = bf16_rne((__expf(xw - P.ss) + EPSF) * SCALE);
            nk[reg] = bf16_rne((__expf(-xw - P.ss) + EPSF) * SCALE);
          }
          *(s4v*)(qf + t_loc * QF_P + ft * 16 + q * 4) = pk;
          *(s4v*)(qf + t_loc * QF_P + 128 + ft * 16 + q * 4) = nk;
        }
      }
      f4v acc[5];
#pragma unroll
      for (int n = 0; n < 5; ++n) acc[n] = f4v{0.f, 0.f, 0.f, 0.f};
      const short* kvb = kvfrag + (size_t)b * 40 * 512;
#pragma unroll
      for (int ks = 0; ks < 8; ++ks) {
        s8v a = *(const s8v*)(qf + (w * 16 + r15) * QF_P + ks * 32 + q * 8);
#pragma unroll
        for (int n = 0; n < 5; ++n) {
          s8v bf = *(const s8v*)(kvb + ((size_t)(ks * 5 + n)) * 512 + lane * 8);
          acc[n] = mfma16(a, bf, acc[n]);
        }
      }
      float den_r[4];
#pragma unroll
      for (int reg = 0; reg < 4; ++reg) den_r[reg] = __shfl(acc[4][reg], lane & 48, 64);
      float* stg = (float*)(qf + w * 16 * QF_P);  // wave-private staging
#pragma unroll
      for (int n = 0; n < 4; ++n)
#pragma unroll
        for (int reg = 0; reg < 4; ++reg) {
          int row = q * 4 + reg;
          int col = n * 16 + r15;
          stg[row * 68 + col] = acc[n][reg] / den_r[reg];
        }
      float* ob = out + ((size_t)b * NT + t0 + w * 16) * 64;
#pragma unroll
      for (int rr = 0; rr < 4; ++rr) {
        int row = rr * 4 + q;
        int c4 = r15 * 4;
        *(f4v*)(ob + row * 64 + c4) = *(const f4v*)(stg + row * 68 + c4);
      }
    }
  }
}

// ================= R4 fallback kernels (proven) =================
__global__ __launch_bounds__(256, 4) void kv_fused(
    const float* __restrict__ key, const float* __restrict__ value,
    const short* __restrict__ oh, const short* __restrict__ ol,
    short* __restrict__ partial, float* __restrict__ kvacc, int use_partial) {
  __shared__ short kft[128 * KF_P];
  __shared__ short v1t[80 * KF_P];
  const int tid = threadIdx.x, lane = tid & 63, w = tid >> 6;
  const int b = blockIdx.x >> 7;
  const int cb = blockIdx.x & 127;
  const int fh = cb & 1;
  const int s0 = (cb >> 1) * 128;
  const int q = lane >> 4, r15 = lane & 15;

  for (int i = tid; i < 15 * KF_P; i += 256) v1t[65 * KF_P + i] = 0;

  f4v acc[2][5];
#pragma unroll
  for (int j = 0; j < 2; ++j)
#pragma unroll
    for (int n = 0; n < 5; ++n) acc[j][n] = f4v{0.f, 0.f, 0.f, 0.f};

  for (int sc = 0; sc < 2; ++sc) {
    const int sbase = s0 + sc * 64;
    __syncthreads();
    {
      const float* vb = value + ((size_t)b * NT + sbase) * 64;
#pragma unroll
      for (int i = 0; i < 4; ++i) {
        int e4 = tid + i * 256;
        f4v v4 = ((const f4v*)vb)[e4];
        int s = e4 >> 4, d0 = (e4 & 15) * 4;
        v1t[(d0 + 0) * KF_P + s] = bf16_rne(v4.x);
        v1t[(d0 + 1) * KF_P + s] = bf16_rne(v4.y);
        v1t[(d0 + 2) * KF_P + s] = bf16_rne(v4.z);
        v1t[(d0 + 3) * KF_P + s] = bf16_rne(v4.w);
      }
      if (tid < 64) v1t[64 * KF_P + tid] = (short)0x3F80;
    }
    {
      PhiRows P;
      load_phi_rows(key + ((size_t)b * NT + sbase + w * 16) * 64, lane, P);
#pragma unroll
      for (int ft = 0; ft < 4; ++ft) {
        f4v c = phi_xw_tile(P, oh, ol, fh * 64 + ft * 16, lane);
        s4v pk, nk;
#pragma unroll
        for (int reg = 0; reg < 4; ++reg) {
          float xw = c[reg];
          pk[reg] = bf16_rne((__expf(xw - P.ssr[reg]) + EPSF) * SCALE);
          nk[reg] = bf16_rne((__expf(-xw - P.ssr[reg]) + EPSF) * SCALE);
        }
        const int scol = w * 16 + q * 4;
        *(s4v*)(kft + (ft * 16 + r15) * KF_P + scol) = pk;
        *(s4v*)(kft + (64 + ft * 16 + r15) * KF_P + scol) = nk;
      }
    }
    __syncthreads();
#pragma unroll
    for (int ks = 0; ks < 2; ++ks) {
      s8v bf[5];
#pragma unroll
      for (int n = 0; n < 5; ++n)
        bf[n] = *(const s8v*)(v1t + (n * 16 + r15) * KF_P + ks * 32 + q * 8);
#pragma unroll
      for (int j = 0; j < 2; ++j) {
        s8v a = *(const s8v*)(kft + (w * 32 + j * 16 + r15) * KF_P + ks * 32 + q * 8);
#pragma unroll
        for (int n = 0; n < 5; ++n) acc[j][n] = mfma16(a, bf[n], acc[j][n]);
      }
    }
  }
  if (use_partial) {
    short* pb = partial + (size_t)blockIdx.x * (80 * 128);
#pragma unroll
    for (int j = 0; j < 2; ++j)
#pragma unroll
      for (int n = 0; n < 5; ++n) {
        int d = n * 16 + r15;
        int lf = w * 32 + j * 16 + q * 4;
        s4v pk;
#pragma unroll
        for (int reg = 0; reg < 4; ++reg) pk[reg] = bf16_rne(acc[j][n][reg]);
        *(s4v*)(pb + d * 128 + lf) = pk;
      }
  } else {
    float* pb = kvacc + (size_t)b * (80 * 256);
#pragma unroll
    for (int j = 0; j < 2; ++j)
#pragma unroll
      for (int n = 0; n < 5; ++n) {
        int d = n * 16 + r15;
        int lf = w * 32 + j * 16 + q * 4;
#pragma unroll
        for (int reg = 0; reg < 4; ++reg) {
          int lfx = lf + reg;
          int m = ((lfx & 63) + fh * 64) + 128 * (lfx >> 6);
          atomicAdd(pb + d * 256 + m, acc[j][n][reg]);
        }
      }
  }
}

__global__ __launch_bounds__(256) void kv_finalize(
    const short* __restrict__ partial, const float* __restrict__ kvacc,
    short* __restrict__ kvfrag, int use_partial) {
  int i = blockIdx.x * 256 + threadIdx.x;
  int b = i / 20480;
  int rem = i - b * 20480;
  int d = rem >> 8;
  int m = rem & 255;
  float s = 0.f;
  if (use_partial) {
    int o = m & 127, sg = m >> 7;
    int fh = o >> 6;
    int lf = (o & 63) + (sg << 6);
    const short* p = partial + ((size_t)(b * 128 + fh)) * (80 * 128) + d * 128 + lf;
#pragma unroll 8
    for (int c = 0; c < 64; ++c) s += bf16_to_f(p[(size_t)c * 2 * (80 * 128)]);
  } else {
    s = kvacc[(size_t)(b * 80 + d) * 256 + m];
  }
  int ks = m >> 5, qq = (m >> 3) & 3, j = m & 7;
  int n = d >> 4, r = d & 15;
  int lane = qq * 16 + r;
  kvfrag[(((size_t)b * 40 + ks * 5 + n) * 64 + lane) * 8 + j] = bf16_rne(s);
}

__global__ __launch_bounds__(256, 4) void qkv_fused(
    const float* __restrict__ query, const short* __restrict__ oh,
    const short* __restrict__ ol, const short* __restrict__ kvfrag,
    float* __restrict__ out) {
  __shared__ __align__(16) short qf[64 * QF_P];
  const int tid = threadIdx.x, lane = tid & 63, w = tid >> 6;
  const int b = blockIdx.x >> 7;
  const int t0 = (blockIdx.x & 127) * 64;
  const int q = lane >> 4, r15 = lane & 15;
  {
    PhiRows P;
    load_phi_rows(query + ((size_t)b * NT + t0 + w * 16) * 64, lane, P);
    const int t_loc = w * 16 + r15;
#pragma unroll
    for (int ft = 0; ft < 8; ++ft) {
      f4v c = phi_xw_tile_T(P, oh, ol, ft * 16, lane);
      s4v pk, nk;
#pragma unroll
      for (int reg = 0; reg < 4; ++reg) {
        float xw = c[reg];
        pk[reg] = bf16_rne((__expf(xw - P.ss) + EPSF) * SCALE);
        nk[reg] = bf16_rne((__expf(-xw - P.ss) + EPSF) * SCALE);
      }
      *(s4v*)(qf + t_loc * QF_P + ft * 16 + q * 4) = pk;
      *(s4v*)(qf + t_loc * QF_P + 128 + ft * 16 + q * 4) = nk;
    }
  }
  f4v acc[5];
#pragma unroll
  for (int n = 0; n < 5; ++n) acc[n] = f4v{0.f, 0.f, 0.f, 0.f};
  const short* kvb = kvfrag + (size_t)b * 40 * 512;
#pragma unroll
  for (int ks = 0; ks < 8; ++ks) {
    s8v a = *(const s8v*)(qf + (w * 16 + r15) * QF_P + ks * 32 + q * 8);
#pragma unroll
    for (int n = 0; n < 5; ++n) {
      s8v bf = *(const s8v*)(kvb + ((size_t)(ks * 5 + n)) * 512 + lane * 8);
      acc[n] = mfma16(a, bf, acc[n]);
    }
  }
  float den_r[4];
#pragma unroll
  for (int reg = 0; reg < 4; ++reg) den_r[reg] = __shfl(acc[4][reg], lane & 48, 64);
  float* stg = (float*)(qf + w * 16 * QF_P);
#pragma unroll
  for (int n = 0; n < 4; ++n)
#pragma unroll
    for (int reg = 0; reg < 4; ++reg) {
      int row = q * 4 + reg;
      int col = n * 16 + r15;
      stg[row * 68 + col] = acc[n][reg] / den_r[reg];
    }
  float* ob = out + ((size_t)b * NT + t0 + w * 16) * 64;
#pragma unroll
  for (int rr = 0; rr < 4; ++rr) {
    int row = rr * 4 + q;
    int c4 = r15 * 4;
    *(f4v*)(ob + row * 64 + c4) = *(const f4v*)(stg + row * 68 + c4);
  }
}

extern "C" void kernel_launch(void* const* d_in, const int* in_sizes, int n_in,
                              void* d_out, int out_size, void* d_ws, size_t ws_size,
                              hipStream_t stream) {
  const float* query = (const float*)d_in[0];  // [8][8192][64]
  const float* value = (const float*)d_in[1];  // [8][8192][64]
  const float* key   = (const float*)d_in[2];  // [8][8192][64]
  const float* omega = (const float*)d_in[3];  // [128][64]
  float* out = (float*)d_out;

  char* ws = (char*)d_ws;
  short* oh = (short*)ws;                        // 16384 B
  short* ol = (short*)(ws + 16384);              // 16384 B
  short* kvfrag = (short*)(ws + 32768);          // 8*40*512*2 = 327680 B
  short* partial = (short*)(ws + 360448);        // 1024*80*128*2 = 20971520 B
  float* kvacc = (float*)(ws + 360448);          // fallback: 8*80*256*4 = 655360 B
  const size_t need_full = 360448 + (size_t)1024 * 80 * 128 * 2;  // ~21.3 MB
  const int use_partial = (ws_size >= need_full) ? 1 : 0;

  setup_omega<<<32, 256, 0, stream>>>(omega, oh, ol);

  bool fused_ok = false;
  if (use_partial) {
    int num_cu = 0, maxb = 0;
    hipDeviceGetAttribute(&num_cu, hipDeviceAttributeMultiprocessorCount, 0);
    hipOccupancyMaxActiveBlocksPerMultiprocessor(&maxb, (const void*)fused_all, 256, 0);
    int g = maxb * num_cu;
    if (g > 1024) g = 1024;
    if (g >= 64) {
      int nblk = g;
      void* args[] = {(void*)&query, (void*)&value, (void*)&key, (void*)&oh,
                      (void*)&ol, (void*)&partial, (void*)&kvfrag, (void*)&out,
                      (void*)&nblk};
      hipError_t e = hipLaunchCooperativeKernel((void*)fused_all, dim3(g), dim3(256),
                                                args, 0, stream);
      fused_ok = (e == hipSuccess);
    }
  }
  if (!fused_ok) {
    if (!use_partial) {
      hipMemsetAsync(kvacc, 0, (size_t)8 * 80 * 256 * 4, stream);
    }
    kv_fused<<<1024, 256, 0, stream>>>(key, value, oh, ol, partial, kvacc, use_partial);
    kv_finalize<<<640, 256, 0, stream>>>(partial, kvacc, kvfrag, use_partial);
    qkv_fused<<<1024, 256, 0, stream>>>(query, oh, ol, kvfrag, out);
  }
}

// Round 6
// 143.108 us; speedup vs baseline: 2.9223x; 2.9223x over previous
//
#include <hip/hip_runtime.h>

// LinearAttention (Performer/FAVOR+): B=8, T=S=8192, F=D=64, M=128 (2M=256 features)
// R6: revert R5 cooperative fusion (VGPR-squeeze -> spills, 3.5x regression).
// R4 3-kernel structure + full-feature kv blocks (halve K/V fetch) + trimmed
// partials (65 of 80 d-rows -> -20% partial traffic, simpler finalize).
//
// MFMA 16x16x32 bf16 layouts (measured, learn_hip m89/m91):
//   A-frag: lane holds A[m = lane&15][k = (lane>>4)*8 + j], j=0..7
//   B-frag: lane holds B[k = (lane>>4)*8 + j][n = lane&15]
//   C/D   : lane holds D[row = (lane>>4)*4 + reg][col = lane&15], reg=0..3

constexpr int NB = 8;
constexpr int NT = 8192;
constexpr float EPSF = 1e-9f;
constexpr float SCALE = 0.0625f;  // 1/sqrt(2*128)

typedef short s8v __attribute__((ext_vector_type(8)));
typedef short s4v __attribute__((ext_vector_type(4)));
typedef float f4v __attribute__((ext_vector_type(4)));

__device__ inline f4v mfma16(s8v a, s8v b, f4v c) {
  return __builtin_amdgcn_mfma_f32_16x16x32_bf16(a, b, c, 0, 0, 0);
}

__device__ inline short bf16_rne(float f) {
  unsigned u = __builtin_bit_cast(unsigned, f);
  u += 0x7fffu + ((u >> 16) & 1u);
  return (short)(u >> 16);
}
__device__ inline float bf16_to_f(short h) {
  unsigned u = ((unsigned)(unsigned short)h) << 16;
  return __builtin_bit_cast(float, u);
}

// ---- setup: split omega into bf16 hi/lo (Markidis 3-term split keeps the
// pre-exp x.omega GEMM at ~fp32 accuracy) ----
__global__ void setup_omega(const float* __restrict__ omega,
                            short* __restrict__ oh, short* __restrict__ ol) {
  int i = blockIdx.x * 256 + threadIdx.x;
  if (i >= 128 * 64) return;
  float w = omega[i];
  short h = bf16_rne(w);
  oh[i] = h;
  ol[i] = bf16_rne(w - bf16_to_f(h));
}

// ---- shared phi helpers ----
struct PhiRows {
  s8v ah0, al0, ah1, al1;  // x fragments (hi/lo) for ksteps 0,1
  float ssr[4];            // |x_row|^2/2 for rows quad*4+reg (C-row indexed)
  float ss;                // |x_row|^2/2 for this lane's own row (lane&15)
};

__device__ inline void split8(f4v a, f4v b, s8v& h, s8v& l) {
  float v[8] = {a.x, a.y, a.z, a.w, b.x, b.y, b.z, b.w};
#pragma unroll
  for (int j = 0; j < 8; ++j) {
    short hh = bf16_rne(v[j]);
    h[j] = hh;
    l[j] = bf16_rne(v[j] - bf16_to_f(hh));
  }
}

__device__ inline void load_phi_rows(const float* __restrict__ xrow_base, int lane, PhiRows& P) {
  const int r = lane & 15, q = lane >> 4;
  const float* p = xrow_base + r * 64 + q * 8;
  f4v u0 = *(const f4v*)(p);
  f4v u1 = *(const f4v*)(p + 4);
  f4v u2 = *(const f4v*)(p + 32);
  f4v u3 = *(const f4v*)(p + 36);
  float ss = u0.x * u0.x + u0.y * u0.y + u0.z * u0.z + u0.w * u0.w
           + u1.x * u1.x + u1.y * u1.y + u1.z * u1.z + u1.w * u1.w
           + u2.x * u2.x + u2.y * u2.y + u2.z * u2.z + u2.w * u2.w
           + u3.x * u3.x + u3.y * u3.y + u3.z * u3.z + u3.w * u3.w;
  ss += __shfl_xor(ss, 16, 64);
  ss += __shfl_xor(ss, 32, 64);
  ss *= 0.5f;
  P.ss = ss;
#pragma unroll
  for (int reg = 0; reg < 4; ++reg) P.ssr[reg] = __shfl(ss, q * 4 + reg, 64);
  split8(u0, u1, P.ah0, P.al0);
  split8(u2, u3, P.ah1, P.al1);
}

// xw C-tile, A = x rows (C: row = x-row q*4+reg, col = omega-row lane&15)
__device__ inline f4v phi_xw_tile(const PhiRows& P, const short* __restrict__ oh,
                                  const short* __restrict__ ol, int f0, int lane) {
  const int fr = f0 + (lane & 15);
  const int q = lane >> 4;
  s8v bh0 = *(const s8v*)(oh + fr * 64 + q * 8);
  s8v bh1 = *(const s8v*)(oh + fr * 64 + 32 + q * 8);
  s8v bl0 = *(const s8v*)(ol + fr * 64 + q * 8);
  s8v bl1 = *(const s8v*)(ol + fr * 64 + 32 + q * 8);
  f4v c = {0.f, 0.f, 0.f, 0.f};
  c = mfma16(P.ah0, bh0, c);
  c = mfma16(P.ah1, bh1, c);
  c = mfma16(P.al0, bh0, c);
  c = mfma16(P.al1, bh1, c);
  c = mfma16(P.ah0, bl0, c);
  c = mfma16(P.ah1, bl1, c);
  return c;
}

// xw C-tile, swapped: A = omega rows (C: row = omega-row q*4+reg, col = x-row lane&15).
// x fragments serve as B unchanged: A-frag and B-frag share the per-lane layout.
__device__ inline f4v phi_xw_tile_T(const PhiRows& P, const short* __restrict__ oh,
                                    const short* __restrict__ ol, int f0, int lane) {
  const int fr = f0 + (lane & 15);
  const int q = lane >> 4;
  s8v ah0 = *(const s8v*)(oh + fr * 64 + q * 8);
  s8v ah1 = *(const s8v*)(oh + fr * 64 + 32 + q * 8);
  s8v al0 = *(const s8v*)(ol + fr * 64 + q * 8);
  s8v al1 = *(const s8v*)(ol + fr * 64 + 32 + q * 8);
  f4v c = {0.f, 0.f, 0.f, 0.f};
  c = mfma16(ah0, P.ah0, c);
  c = mfma16(ah1, P.ah1, c);
  c = mfma16(al0, P.ah0, c);
  c = mfma16(al1, P.ah1, c);
  c = mfma16(ah0, P.al0, c);
  c = mfma16(ah1, P.al1, c);
  return c;
}

constexpr int KF_P = 72;          // kft/v1t pitch in shorts
constexpr int QF_P = 264;         // qf pitch (shorts): 256 + 8 pad
constexpr int PART_SZ = 65 * 256; // trimmed partial tile (floats->bf16 shorts)

// ---- Kernel KV: fused phi(k) + kv GEMM, full 256 features per block ----
// grid 512 = 8b x 64 s-chunks(128). partial[blk][d=0..64][m=0..255] bf16 -> 17 MB.
__global__ __launch_bounds__(256, 2) void kv_fused(
    const float* __restrict__ key, const float* __restrict__ value,
    const short* __restrict__ oh, const short* __restrict__ ol,
    short* __restrict__ partial, float* __restrict__ kvacc, int use_partial) {
  __shared__ short kft[256 * KF_P];  // [feat][s] bf16, 36864 B
  __shared__ short v1t[80 * KF_P];   // [d][s] bf16, 11520 B
  const int tid = threadIdx.x, lane = tid & 63, w = tid >> 6;
  const int b = blockIdx.x >> 6;
  const int s0 = (blockIdx.x & 63) * 128;
  const int q = lane >> 4, r15 = lane & 15;

  // zero v1t pad rows 65..79 (N=80 tile columns beyond [v|1])
  for (int i = tid; i < 15 * KF_P; i += 256) v1t[65 * KF_P + i] = 0;

  f4v acc[4][5];
#pragma unroll
  for (int j = 0; j < 4; ++j)
#pragma unroll
    for (int n = 0; n < 5; ++n) acc[j][n] = f4v{0.f, 0.f, 0.f, 0.f};

  for (int sc = 0; sc < 2; ++sc) {
    const int sbase = s0 + sc * 64;
    __syncthreads();  // protect previous iteration's GEMM reads
    // stage v1t[d][s] (transposed, bf16); f4v global loads
    {
      const float* vb = value + ((size_t)b * NT + sbase) * 64;
#pragma unroll
      for (int i = 0; i < 4; ++i) {
        int e4 = tid + i * 256;           // f4v index
        f4v v4 = ((const f4v*)vb)[e4];
        int s = e4 >> 4, d0 = (e4 & 15) * 4;
        v1t[(d0 + 0) * KF_P + s] = bf16_rne(v4.x);
        v1t[(d0 + 1) * KF_P + s] = bf16_rne(v4.y);
        v1t[(d0 + 2) * KF_P + s] = bf16_rne(v4.z);
        v1t[(d0 + 3) * KF_P + s] = bf16_rne(v4.w);
      }
      if (tid < 64) v1t[64 * KF_P + tid] = (short)0x3F80;  // bf16(1.0)
    }
    // phi(k): wave w -> s-rows sbase+w*16..+15, all 8 omega tiles (256 feats)
    {
      PhiRows P;
      load_phi_rows(key + ((size_t)b * NT + sbase + w * 16) * 64, lane, P);
#pragma unroll
      for (int ft = 0; ft < 8; ++ft) {
        f4v c = phi_xw_tile(P, oh, ol, ft * 16, lane);
        s4v pk, nk;
#pragma unroll
        for (int reg = 0; reg < 4; ++reg) {
          float xw = c[reg];
          pk[reg] = bf16_rne((__expf(xw - P.ssr[reg]) + EPSF) * SCALE);
          nk[reg] = bf16_rne((__expf(-xw - P.ssr[reg]) + EPSF) * SCALE);
        }
        const int scol = w * 16 + q * 4;
        *(s4v*)(kft + (ft * 16 + r15) * KF_P + scol) = pk;         // feat [0,128)
        *(s4v*)(kft + (128 + ft * 16 + r15) * KF_P + scol) = nk;   // feat [128,256)
      }
    }
    __syncthreads();
    // GEMM: wave w accumulates feats w*64..+63 over all 64 s
#pragma unroll
    for (int ks = 0; ks < 2; ++ks) {
      s8v bf[5];
#pragma unroll
      for (int n = 0; n < 5; ++n)
        bf[n] = *(const s8v*)(v1t + (n * 16 + r15) * KF_P + ks * 32 + q * 8);
#pragma unroll
      for (int j = 0; j < 4; ++j) {
        s8v a = *(const s8v*)(kft + (w * 64 + j * 16 + r15) * KF_P + ks * 32 + q * 8);
#pragma unroll
        for (int n = 0; n < 5; ++n) acc[j][n] = mfma16(a, bf[n], acc[j][n]);
      }
    }
  }
  // epilogue: C row = feat m (w*64+j*16+q*4+reg), col = d (n*16+r15); keep d<=64
  if (use_partial) {
    short* pb = partial + (size_t)blockIdx.x * PART_SZ;
#pragma unroll
    for (int j = 0; j < 4; ++j) {
      int m = w * 64 + j * 16 + q * 4;
#pragma unroll
      for (int n = 0; n < 4; ++n) {
        int d = n * 16 + r15;
        s4v pk;
#pragma unroll
        for (int reg = 0; reg < 4; ++reg) pk[reg] = bf16_rne(acc[j][n][reg]);
        *(s4v*)(pb + d * 256 + m) = pk;
      }
      if (r15 == 0) {  // n=4 tile: only d=64 is real
        s4v pk;
#pragma unroll
        for (int reg = 0; reg < 4; ++reg) pk[reg] = bf16_rne(acc[j][4][reg]);
        *(s4v*)(pb + 64 * 256 + m) = pk;
      }
    }
  } else {
    float* pb = kvacc + (size_t)b * PART_SZ;
#pragma unroll
    for (int j = 0; j < 4; ++j) {
      int m = w * 64 + j * 16 + q * 4;
#pragma unroll
      for (int n = 0; n < 4; ++n) {
        int d = n * 16 + r15;
#pragma unroll
        for (int reg = 0; reg < 4; ++reg) atomicAdd(pb + d * 256 + m + reg, acc[j][n][reg]);
      }
      if (r15 == 0)
#pragma unroll
        for (int reg = 0; reg < 4; ++reg) atomicAdd(pb + 64 * 256 + m + reg, acc[j][4][reg]);
    }
  }
}

// ---- Kernel finalize: reduce bf16 partials -> kvfrag (B-fragment order) ----
// kvfrag[b][fid=ks*5+n][lane][j]: lane holds B[k=ks*32+(lane>>4)*8+j][d=n*16+(lane&15)]
// d in [65,80) pad slots are written 0.
__global__ __launch_bounds__(256) void kv_finalize(
    const short* __restrict__ partial, const float* __restrict__ kvacc,
    short* __restrict__ kvfrag, int use_partial) {
  int i = blockIdx.x * 256 + threadIdx.x;  // 163840 outputs: (b, d=0..79, m)
  int b = i / 20480;
  int rem = i - b * 20480;
  int d = rem >> 8;
  int m = rem & 255;
  float s = 0.f;
  if (d < 65) {
    if (use_partial) {
      const short* p = partial + (size_t)(b * 64) * PART_SZ + d * 256 + m;
#pragma unroll 8
      for (int c = 0; c < 64; ++c) s += bf16_to_f(p[(size_t)c * PART_SZ]);
    } else {
      s = kvacc[(size_t)b * PART_SZ + d * 256 + m];
    }
  }
  int ks = m >> 5, qq = (m >> 3) & 3, j = m & 7;
  int n = d >> 4, r = d & 15;
  int lane = qq * 16 + r;
  kvfrag[(((size_t)b * 40 + ks * 5 + n) * 64 + lane) * 8 + j] = bf16_rne(s);
}

// ---- Kernel QKV: fused phi(q) + qkv GEMM + normalize ----
// grid 1024 = 8b x 128 t-chunks(64). qf is wave-private -> no barriers.
__global__ __launch_bounds__(256, 4) void qkv_fused(
    const float* __restrict__ query, const short* __restrict__ oh,
    const short* __restrict__ ol, const short* __restrict__ kvfrag,
    float* __restrict__ out) {
  __shared__ __align__(16) short qf[64 * QF_P];  // [t][feat] bf16, 33792 B
  const int tid = threadIdx.x, lane = tid & 63, w = tid >> 6;
  const int b = blockIdx.x >> 7;
  const int t0 = (blockIdx.x & 127) * 64;
  const int q = lane >> 4, r15 = lane & 15;

  // phi(q), swapped operands: C row = omega-row, col = t -> packed s4v writes
  {
    PhiRows P;
    load_phi_rows(query + ((size_t)b * NT + t0 + w * 16) * 64, lane, P);
    const int t_loc = w * 16 + r15;
#pragma unroll
    for (int ft = 0; ft < 8; ++ft) {
      f4v c = phi_xw_tile_T(P, oh, ol, ft * 16, lane);
      s4v pk, nk;
#pragma unroll
      for (int reg = 0; reg < 4; ++reg) {
        float xw = c[reg];  // feature ft*16+q*4+reg for x-row r15 (own ss)
        pk[reg] = bf16_rne((__expf(xw - P.ss) + EPSF) * SCALE);
        nk[reg] = bf16_rne((__expf(-xw - P.ss) + EPSF) * SCALE);
      }
      *(s4v*)(qf + t_loc * QF_P + ft * 16 + q * 4) = pk;
      *(s4v*)(qf + t_loc * QF_P + 128 + ft * 16 + q * 4) = nk;
    }
  }
  // GEMM: wave w's A rows = its own 16 t-rows; B-frags straight from global (L2)
  f4v acc[5];
#pragma unroll
  for (int n = 0; n < 5; ++n) acc[n] = f4v{0.f, 0.f, 0.f, 0.f};
  const short* kvb = kvfrag + (size_t)b * 40 * 512;
#pragma unroll
  for (int ks = 0; ks < 8; ++ks) {
    s8v a = *(const s8v*)(qf + (w * 16 + r15) * QF_P + ks * 32 + q * 8);
#pragma unroll
    for (int n = 0; n < 5; ++n) {
      s8v bf = *(const s8v*)(kvb + ((size_t)(ks * 5 + n)) * 512 + lane * 8);
      acc[n] = mfma16(a, bf, acc[n]);
    }
  }
  // denominator: N-tile 4 col 0 (d=64) holds den for rows q*4+reg
  float den_r[4];
#pragma unroll
  for (int reg = 0; reg < 4; ++reg) den_r[reg] = __shfl(acc[4][reg], lane & 48, 64);
  // normalize + stage into this wave's own qf region (its A-reads are done)
  float* stg = (float*)(qf + w * 16 * QF_P);  // 16x68 f32 = 4352 B < 8448 B region
#pragma unroll
  for (int n = 0; n < 4; ++n)
#pragma unroll
    for (int reg = 0; reg < 4; ++reg) {
      int row = q * 4 + reg;
      int col = n * 16 + r15;
      stg[row * 68 + col] = acc[n][reg] / den_r[reg];
    }
  // coalesced copy out (wave-private)
  float* ob = out + ((size_t)b * NT + t0 + w * 16) * 64;
#pragma unroll
  for (int rr = 0; rr < 4; ++rr) {
    int row = rr * 4 + q;
    int c4 = r15 * 4;
    *(f4v*)(ob + row * 64 + c4) = *(const f4v*)(stg + row * 68 + c4);
  }
}

extern "C" void kernel_launch(void* const* d_in, const int* in_sizes, int n_in,
                              void* d_out, int out_size, void* d_ws, size_t ws_size,
                              hipStream_t stream) {
  const float* query = (const float*)d_in[0];  // [8][8192][64]
  const float* value = (const float*)d_in[1];  // [8][8192][64]
  const float* key   = (const float*)d_in[2];  // [8][8192][64]
  const float* omega = (const float*)d_in[3];  // [128][64]
  float* out = (float*)d_out;

  char* ws = (char*)d_ws;
  short* oh = (short*)ws;                        // 16384 B
  short* ol = (short*)(ws + 16384);              // 16384 B
  short* kvfrag = (short*)(ws + 32768);          // 8*40*512*2 = 327680 B
  short* partial = (short*)(ws + 360448);        // 512*65*256*2 = 17039360 B
  float* kvacc = (float*)(ws + 360448);          // fallback: 8*65*256*4 = 532480 B
  const size_t need_full = 360448 + (size_t)512 * PART_SZ * 2;  // ~17.4 MB
  const int use_partial = (ws_size >= need_full) ? 1 : 0;

  setup_omega<<<32, 256, 0, stream>>>(omega, oh, ol);
  if (!use_partial) {
    hipMemsetAsync(kvacc, 0, (size_t)8 * PART_SZ * 4, stream);  // atomic targets
  }
  kv_fused<<<512, 256, 0, stream>>>(key, value, oh, ol, partial, kvacc, use_partial);
  kv_finalize<<<640, 256, 0, stream>>>(partial, kvacc, kvfrag, use_partial);
  qkv_fused<<<1024, 256, 0, stream>>>(query, oh, ol, kvfrag, out);
}